// Round 2
// baseline (811.777 us; speedup 1.0000x reference)
//
#include <hip/hip_runtime.h>
#include <math.h>

#define B_   4
#define S_   2048
#define DIM_ 1024
#define NH_  8
#define DH_  128
#define CS_  16
#define NS_  128
#define EPSv  1e-6f
#define LNEPS 1e-5f

// workspace layout (float offsets), total 401408 floats = 1.6 MB
#define IG_OFF    0        // (B*NH*S) ig
#define LF_OFF    65536    // log-sigmoid(fg)
#define LFACC_OFF 131072   // within-chunk cumsum of lf
#define GEXP_OFF  196608   // exp(ig - lfacc + lfl - mloc)
#define STAB_OFF  262144   // per (bh,n,c) stabilizer
#define DECAY_OFF 327680   // exp(mp + lfacc - stab)
#define A_OFF     393216   // scan coefficient a[n]  (B*NH*NS)
#define BB_OFF    397312   // scan coefficient b[n]

__device__ __forceinline__ float logsig(float x){
  return (x >= 0.f) ? -log1pf(expf(-x)) : (x - log1pf(expf(x)));
}

// ---------------------------------------------------------------- K1: gates
// one wave per 4 rows; W streamed once per wave (4x amortized vs 1 row/wave)
__global__ __launch_bounds__(256) void k_gates(const float* __restrict__ q,
    const float* __restrict__ k, const float* __restrict__ v,
    const float* __restrict__ Wi, const float* __restrict__ bi,
    const float* __restrict__ Wf, const float* __restrict__ bf,
    float* __restrict__ ws){
  int wid  = blockIdx.x*4 + (threadIdx.x>>6);   // wave 0..2047
  int lane = threadIdx.x & 63;
  int r0   = wid*4;                             // 4 rows per wave
  float acc[16][4];
  #pragma unroll
  for (int g=0;g<16;g++){ acc[g][0]=0.f; acc[g][1]=0.f; acc[g][2]=0.f; acc[g][3]=0.f; }
  #pragma unroll
  for (int j=0;j<16;j++){
    int col = lane + 64*j;
    float xq[4], xk[4], xv[4];
    #pragma unroll
    for (int rr=0;rr<4;rr++){
      size_t base = (size_t)(r0+rr)*DIM_ + col;
      xq[rr]=q[base]; xk[rr]=k[base]; xv[rr]=v[base];
    }
    #pragma unroll
    for (int g=0; g<16; g++){
      const float* W = (g<8) ? (Wi + (size_t)g*3072) : (Wf + (size_t)(g-8)*3072);
      float w0=W[col], w1=W[1024+col], w2=W[2048+col];
      #pragma unroll
      for (int rr=0;rr<4;rr++)
        acc[g][rr] += xq[rr]*w0 + xk[rr]*w1 + xv[rr]*w2;
    }
  }
  #pragma unroll
  for (int g=0; g<16; g++)
    #pragma unroll
    for (int rr=0;rr<4;rr++)
      #pragma unroll
      for (int off=32; off>0; off>>=1) acc[g][rr] += __shfl_down(acc[g][rr], off, 64);
  if (lane==0){
    #pragma unroll
    for (int rr=0;rr<4;rr++){
      int r = r0+rr, b = r>>11, s = r&2047;
      #pragma unroll
      for (int h=0; h<8; h++){
        float ig = acc[h][rr]   + bi[h];
        float fg = acc[8+h][rr] + bf[h];
        size_t o = ((size_t)b*NH_ + h)*S_ + s;
        ws[IG_OFF + o] = ig;
        ws[LF_OFF + o] = logsig(fg);
      }
    }
  }
}

// ------------------------------- K2: fused chunk scalars + m-scan + prep
// one block per (b,h)
__global__ __launch_bounds__(256) void k_mid(float* __restrict__ ws,
                                             float* __restrict__ ml_out){
  __shared__ float lfl_s[128], ml_s[128], a_s[128], b_s[128], mp_s[128];
  __shared__ float lfacc_sh[2048], R_sh[2048];
  int bh = blockIdx.x, t = threadIdx.x;
  if (t < 128){
    int n = t; size_t base = (size_t)bh*S_ + n*CS_;
    float lfacc[16], igr[16];
    float cum = 0.f;
    #pragma unroll
    for (int c=0;c<16;c++){ cum += ws[LF_OFF+base+c]; lfacc[c]=cum; igr[c]=ws[IG_OFF+base+c]; }
    float lfl = cum;
    float R = -3.4e38f;
    float Rr[16];
    #pragma unroll
    for (int c=0;c<16;c++){ R = fmaxf(R, igr[c]-lfacc[c]); Rr[c]=R; }
    float mloc = lfl + R;                     // max_c(ig - lfacc + lfl)
    #pragma unroll
    for (int c=0;c<16;c++){
      ws[GEXP_OFF+base+c]  = expf(igr[c]-lfacc[c]+lfl-mloc);
      ws[LFACC_OFF+base+c] = lfacc[c];
      lfacc_sh[n*16+c] = lfacc[c];
      R_sh[n*16+c]     = Rr[c];
    }
    lfl_s[n]=lfl; ml_s[n]=mloc;
  }
  __syncthreads();
  if (t==0){
    float m = 0.f;                            // reference init m=0
    for (int n=0;n<128;n++){
      float mn = fmaxf(lfl_s[n]+m, ml_s[n]);
      a_s[n]=expf(lfl_s[n]+m-mn); b_s[n]=expf(ml_s[n]-mn); mp_s[n]=m; m=mn;
    }
    ml_out[bh]=m;
  }
  __syncthreads();
  if (t < 128){ ws[A_OFF+bh*NS_+t]=a_s[t]; ws[BB_OFF+bh*NS_+t]=b_s[t]; }
  for (int i=t; i<2048; i+=256){
    int n = i>>4;
    float la = lfacc_sh[i], mpv = mp_s[n];
    float stb = fmaxf(la + R_sh[i], mpv + la);   // max(D_max, mp+lfacc)
    ws[STAB_OFF +(size_t)bh*S_+i] = stb;
    ws[DECAY_OFF+(size_t)bh*S_+i] = expf(mpv + la - stb);
  }
}

// --------------------------------------------------------- K3: main scan
// grid = 256: bh = blk&31, eh = blk>>5  (8 e-blocks of a bh share one XCD's L2)
// C state transposed in LDS: C_s[e_local][d], pad 132
__global__ __launch_bounds__(256) void k_main(const float* __restrict__ qg,
    const float* __restrict__ kg, const float* __restrict__ vglob,
    const float* __restrict__ ws, float* __restrict__ out,
    float* __restrict__ Cl, float* __restrict__ nl){
  __shared__ __align__(16) float q_s[16][132];
  __shared__ __align__(16) float k_s[16][132];
  __shared__ __align__(16) float C_s[16][132];
  __shared__ float v_s[16][17], vg_s[16][17], E_s[16][17], pn_s[16][17];
  __shared__ float n_s[128];
  __shared__ float lfacc_s[16], ig_s[16], gexp_s[16], stab_s[16], decay_s[16], rnorm_s[16];
  const int t  = threadIdx.x;
  const int bh = blockIdx.x & 31, eh = blockIdx.x >> 5;
  const int b  = bh >> 3, h = bh & 7;
  const int e0 = eh*CS_;
  const int c_t = t >> 4, e_t = t & 15;
  const int d_t = t & 127, g_t = t >> 7;
  for (int i=t; i<16*132; i+=256) (&C_s[0][0])[i] = 0.f;
  if (t < 128) n_s[t] = 0.f;

  // software-pipelined staging registers
  float pq[8], pk[8], pv, pgx;
  float s_la=0.f, s_ig=0.f, s_gx=0.f, s_st=0.f, s_de=0.f, s_a, s_b;

#define LOADCH(nn) do { \
    const size_t rb = ((size_t)b*S_ + (size_t)(nn)*CS_)*DIM_ + (size_t)h*DH_; \
    const size_t sb = (size_t)bh*S_ + (size_t)(nn)*CS_; \
    _Pragma("unroll") \
    for (int r=0;r<8;r++){ \
      int idx = r*256 + t; int c = idx>>7; int d = idx&127; \
      pq[r] = qg[rb + (size_t)c*DIM_ + d]; \
      pk[r] = kg[rb + (size_t)c*DIM_ + d]; \
    } \
    pv  = vglob[rb + (size_t)c_t*DIM_ + e0 + e_t]; \
    pgx = ws[GEXP_OFF + sb + c_t]; \
    if (t < 16){ \
      s_la = ws[LFACC_OFF + sb + t]; \
      s_ig = ws[IG_OFF    + sb + t]; \
      s_gx = ws[GEXP_OFF  + sb + t]; \
      s_st = ws[STAB_OFF  + sb + t]; \
      s_de = ws[DECAY_OFF + sb + t]; \
    } \
    s_a = ws[A_OFF  + bh*NS_ + (nn)]; \
    s_b = ws[BB_OFF + bh*NS_ + (nn)]; \
  } while(0)

  LOADCH(0);

  for (int n=0; n<NS_; n++){
    const size_t rowbase = ((size_t)b*S_ + (size_t)n*CS_)*DIM_ + (size_t)h*DH_;
    __syncthreads();                      // prev chunk done (and C zero-init)
    // ---- P0: staged regs -> LDS
    #pragma unroll
    for (int r=0;r<8;r++){
      int idx = r*256 + t; int c = idx>>7; int d = idx&127;
      q_s[c][d] = pq[r]*0.08838834764831845f;   // 1/sqrt(128)
      k_s[c][d] = pk[r];
    }
    v_s[c_t][e_t]  = pv;
    vg_s[c_t][e_t] = pv*pgx;
    if (t < 16){
      lfacc_s[t]=s_la; ig_s[t]=s_ig; gexp_s[t]=s_gx; stab_s[t]=s_st; decay_s[t]=s_de;
    }
    const float a_n = s_a, b_n = s_b;
    __syncthreads();
    if (n < NS_-1) LOADCH(n+1);           // prefetch: latency hides under P1-P4
    // ---- P1: E and inter_C partials; pn partials
    float dqk = 0.f, ic = 0.f;
    {
      const float4* q4 = (const float4*)&q_s[c_t][0];
      const float4* k4 = (const float4*)&k_s[e_t][0];
      const float4* C4 = (const float4*)&C_s[e_t][0];
      #pragma unroll
      for (int d4=0; d4<32; d4++){
        float4 qv = q4[d4], kv2 = k4[d4], cv = C4[d4];
        dqk += qv.x*kv2.x + qv.y*kv2.y + qv.z*kv2.z + qv.w*kv2.w;
        ic  += qv.x*cv.x  + qv.y*cv.y  + qv.z*cv.z  + qv.w*cv.w;
      }
    }
    float Ev = 0.f;
    if (e_t <= c_t)
      Ev = dqk * expf(lfacc_s[c_t] - lfacc_s[e_t] + ig_s[e_t] - stab_s[c_t]);
    E_s[c_t][e_t] = Ev;
    if (t < 128){
      int c2 = t>>3, j2 = t&7;
      const float4* qq = (const float4*)&q_s[c2][j2*16];
      const float4* nn4 = (const float4*)&n_s[j2*16];
      float p = 0.f;
      #pragma unroll
      for (int dd=0; dd<4; dd++){
        float4 a = qq[dd], bv = nn4[dd];
        p += a.x*bv.x + a.y*bv.y + a.z*bv.z + a.w*bv.w;
      }
      pn_s[c2][j2] = p;
    }
    __syncthreads();
    // ---- P2: norms
    if (t < 16){
      float pns=0.f, rs=0.f;
      #pragma unroll
      for (int j=0;j<8;j++)  pns += pn_s[t][j];
      #pragma unroll
      for (int cc=0;cc<16;cc++) rs += E_s[t][cc];
      float tot = rs + decay_s[t]*pns;
      float nrm = fmaxf(fabsf(tot), expf(-stab_s[t])) + EPSv;
      rnorm_s[t] = 1.0f/nrm;
    }
    __syncthreads();
    // ---- P3: h output (final (B,S,DIM) layout, pre-LN)
    {
      float hs = 0.f;
      #pragma unroll
      for (int cc=0;cc<16;cc++) hs += E_s[c_t][cc]*v_s[cc][e_t];
      float hv = (hs + decay_s[c_t]*ic)*rnorm_s[c_t];
      out[rowbase + (size_t)c_t*DIM_ + e0 + e_t] = hv;
    }
    // ---- P4: kv + state update (C, n)
    {
      float kv[8] = {0,0,0,0,0,0,0,0};
      #pragma unroll
      for (int c=0;c<16;c++){
        float kc = k_s[c][d_t];
        #pragma unroll
        for (int j=0;j<8;j++) kv[j] += kc*vg_s[c][g_t*8+j];
      }
      #pragma unroll
      for (int j=0;j<8;j++){
        int e = g_t*8+j;
        C_s[e][d_t] = C_s[e][d_t]*a_n + kv[j]*b_n;
      }
      if (t < 128){
        float ks = 0.f;
        #pragma unroll
        for (int c=0;c<16;c++) ks += k_s[c][t]*gexp_s[c];
        n_s[t] = n_s[t]*a_n + ks*b_n;
      }
    }
  }
  __syncthreads();
  #pragma unroll
  for (int j=0;j<8;j++)
    Cl[(size_t)bh*DH_*DH_ + (size_t)d_t*DH_ + e0 + g_t*8 + j] = C_s[g_t*8+j][d_t];
  if (eh==0 && t<128) nl[(size_t)bh*DH_ + t] = n_s[t];
#undef LOADCH
}

// ------------------------------------------------------ K4: in-place LN
__global__ __launch_bounds__(256) void k_ln(float* __restrict__ out,
    const float* __restrict__ lnw, const float* __restrict__ lnb){
  int r = blockIdx.x*4 + (threadIdx.x>>6);
  int lane = threadIdx.x & 63;
  int b = r >> 14;
  int h = (r >> 11) & 7;
  int s = r & 2047;
  size_t base = ((size_t)b*S_ + s)*DIM_ + (size_t)h*DH_;
  float2 x = *(const float2*)&out[base + lane*2];
  float sm = x.x + x.y;
  #pragma unroll
  for (int off=32; off>0; off>>=1) sm += __shfl_xor(sm, off, 64);
  float mu = sm * (1.0f/128.0f);
  float d0 = x.x-mu, d1 = x.y-mu;
  float ss = d0*d0 + d1*d1;
  #pragma unroll
  for (int off=32; off>0; off>>=1) ss += __shfl_xor(ss, off, 64);
  float rstd = 1.0f/sqrtf(ss*(1.0f/128.0f) + LNEPS);
  int wi = h*DH_ + lane*2;
  float2 w2 = *(const float2*)&lnw[wi];
  float2 b2 = *(const float2*)&lnb[wi];
  float2 y;
  y.x = d0*rstd*(1.0f+w2.x) + b2.x;
  y.y = d1*rstd*(1.0f+w2.y) + b2.y;
  *(float2*)&out[base + lane*2] = y;
}

extern "C" void kernel_launch(void* const* d_in, const int* in_sizes, int n_in,
                              void* d_out, int out_size, void* d_ws, size_t ws_size,
                              hipStream_t stream){
  const float* q   = (const float*)d_in[0];
  const float* k   = (const float*)d_in[1];
  const float* v   = (const float*)d_in[2];
  const float* Wi  = (const float*)d_in[3];
  const float* bi  = (const float*)d_in[4];
  const float* Wf  = (const float*)d_in[5];
  const float* bf  = (const float*)d_in[6];
  const float* lnw = (const float*)d_in[7];
  const float* lnb = (const float*)d_in[8];
  float* out = (float*)d_out;                 // (B,S,DIM)
  float* Cl  = out + 8388608;                 // (B,NH,DH,DH)
  float* nl  = out + 8912896;                 // (B,NH,DH)
  float* ml  = out + 8916992;                 // (B,NH,1,1)
  float* ws  = (float*)d_ws;

  k_gates<<<512,  256, 0, stream>>>(q,k,v,Wi,bi,Wf,bf,ws);
  k_mid  <<<32,   256, 0, stream>>>(ws, ml);
  k_main <<<256,  256, 0, stream>>>(q,k,v,ws,out,Cl,nl);
  k_ln   <<<16384,256, 0, stream>>>(out, lnw, lnb);
}